// Round 2
// baseline (446.367 us; speedup 1.0000x reference)
//
#include <hip/hip_runtime.h>
#include <stdint.h>

#define N_NODES 100000
#define N_EDGES 1600000
#define NBLK_SCAN 391   // ceil(N_NODES/256)

typedef __attribute__((ext_vector_type(8))) short short8;
typedef __attribute__((ext_vector_type(4))) float float4v;

__device__ __forceinline__ unsigned short f32_to_bf16(float f) {
  uint32_t u = __float_as_uint(f);
  u += 0x7fffu + ((u >> 16) & 1u);   // RNE
  return (unsigned short)(u >> 16);
}
__device__ __forceinline__ float bf16_to_f32(unsigned short h) {
  return __uint_as_float(((uint32_t)h) << 16);
}

// ---------------------------------------------------------------------------
// K0: out = x@root_w + bias (k2 will += the attention term);
//     r_dot[n] = (x@root_w)[n] . att_w[:32];  zero deg[].
// 8 nodes per 256-thread block, lane = f_out.
// ---------------------------------------------------------------------------
__global__ __launch_bounds__(256) void k0_node_pre(
    const float* __restrict__ x, const float* __restrict__ root_w,
    const float* __restrict__ att_w, const float* __restrict__ bias,
    float* __restrict__ out, float* __restrict__ r_dot, int* __restrict__ deg) {
  __shared__ float rw[32 * 32];
  __shared__ float xs[8 * 32];
  __shared__ float a1[32];
  __shared__ float bs[32];
  int tid = threadIdx.x;
  int n0 = blockIdx.x * 8;
  for (int i = tid; i < 1024; i += 256) rw[i] = root_w[i];
  if (tid < 32) { a1[tid] = att_w[tid]; bs[tid] = bias[tid]; }
  int g = blockIdx.x * 256 + tid;
  if (g < N_NODES) deg[g] = 0;
  int nl = tid >> 5, f = tid & 31;
  int n = n0 + nl;
  xs[tid] = (n < N_NODES) ? x[n * 32 + f] : 0.f;
  __syncthreads();
  float acc = 0.f;
#pragma unroll
  for (int kk = 0; kk < 32; kk++) acc += xs[nl * 32 + kk] * rw[kk * 32 + f];
  if (n < N_NODES) out[n * 32 + f] = acc + bs[f];
  float v = acc * a1[f];
#pragma unroll
  for (int m = 16; m >= 1; m >>= 1) v += __shfl_xor(v, m, 32);
  if (f == 0 && n < N_NODES) r_dot[n] = v;
}

// ---------------------------------------------------------------------------
// KW: weight [25][32][32] fp32 -> bf16, pre-swizzled into MFMA B-fragment
// order: wbf[((t*4+q)*16+c)*8+j], t=km*2+(fo>>4), c=fo&15, q=kk>>3, j=kk&7.
// ---------------------------------------------------------------------------
__global__ __launch_bounds__(256) void kw_swizzle(
    const float* __restrict__ weight, unsigned short* __restrict__ wbf) {
  int e = blockIdx.x * 256 + threadIdx.x;
  if (e >= 25600) return;
  int km = e >> 10;
  int rem = e & 1023;
  int kk = rem >> 5;
  int fo = rem & 31;
  int t = km * 2 + (fo >> 4);
  int c = fo & 15;
  int q = kk >> 3, j = kk & 7;
  wbf[((t * 4 + q) * 16 + c) * 8 + j] = f32_to_bf16(weight[e]);
}

// ---------------------------------------------------------------------------
// K1: xw[n][km*32+fo] = (x @ W_km)[n][fo] in bf16. 16 nodes per block.
// MFMA 16x16x32: A-frag direct from x (lane m=lane&15, k=quad*8+j);
// B-frag direct from pre-swizzled wbf. Results staged to LDS, then one
// fully-coalesced uint4 store of the 16x800 tile.
// ---------------------------------------------------------------------------
__global__ __launch_bounds__(256) void k1_xw(
    const float* __restrict__ x, const unsigned short* __restrict__ wbf,
    unsigned short* __restrict__ xw) {
  __shared__ __align__(16) unsigned short ot[16 * 800];
  int tid = threadIdx.x;
  int wave = tid >> 6, lane = tid & 63;
  int quad = lane >> 4, c16 = lane & 15;
  int n0 = blockIdx.x * 16;
  const float* xp = x + (size_t)(n0 + c16) * 32 + quad * 8;
  float4 a0 = *reinterpret_cast<const float4*>(xp);
  float4 a1 = *reinterpret_cast<const float4*>(xp + 4);
  short8 af;
  af[0] = (short)f32_to_bf16(a0.x); af[1] = (short)f32_to_bf16(a0.y);
  af[2] = (short)f32_to_bf16(a0.z); af[3] = (short)f32_to_bf16(a0.w);
  af[4] = (short)f32_to_bf16(a1.x); af[5] = (short)f32_to_bf16(a1.y);
  af[6] = (short)f32_to_bf16(a1.z); af[7] = (short)f32_to_bf16(a1.w);
  for (int t = wave; t < 50; t += 4) {
    short8 bf = *reinterpret_cast<const short8*>(wbf + ((t * 4 + quad) * 16 + c16) * 8);
    float4v acc = {0.f, 0.f, 0.f, 0.f};
    acc = __builtin_amdgcn_mfma_f32_16x16x32_bf16(af, bf, acc, 0, 0, 0);
    int cg = t * 16 + c16;
#pragma unroll
    for (int r = 0; r < 4; r++) ot[(quad * 4 + r) * 800 + cg] = f32_to_bf16(acc[r]);
  }
  __syncthreads();
  const uint4* src = (const uint4*)ot;
  uint4* dst = (uint4*)(xw + (size_t)n0 * 800);
  for (int i = tid; i < 1600; i += 256) dst[i] = src[i];
}

// ---------------------------------------------------------------------------
// CSR build: histogram -> 2-level exclusive scan -> scatter (8B packets).
// ---------------------------------------------------------------------------
__global__ __launch_bounds__(256) void khist(const int* __restrict__ ei,
                                             int* __restrict__ deg) {
  int e = blockIdx.x * 256 + threadIdx.x;
  if (e < N_EDGES) atomicAdd(&deg[ei[e]], 1);
}

__global__ __launch_bounds__(256) void kscan1(const int* __restrict__ deg,
                                              int* __restrict__ incl,
                                              int* __restrict__ bsum) {
  __shared__ int s[256];
  int tid = threadIdx.x;
  int i = blockIdx.x * 256 + tid;
  int v = (i < N_NODES) ? deg[i] : 0;
  s[tid] = v;
  __syncthreads();
  for (int d = 1; d < 256; d <<= 1) {
    int t = (tid >= d) ? s[tid - d] : 0;
    __syncthreads();
    s[tid] += t;
    __syncthreads();
  }
  if (i < N_NODES) incl[i] = s[tid];
  if (tid == 255) bsum[blockIdx.x] = s[255];
}

__global__ __launch_bounds__(512) void kscan2(const int* __restrict__ bsum,
                                              int* __restrict__ bbase) {
  __shared__ int s[512];
  int tid = threadIdx.x;
  int v = (tid < NBLK_SCAN) ? bsum[tid] : 0;
  s[tid] = v;
  __syncthreads();
  for (int d = 1; d < 512; d <<= 1) {
    int t = (tid >= d) ? s[tid - d] : 0;
    __syncthreads();
    s[tid] += t;
    __syncthreads();
  }
  if (tid < NBLK_SCAN) bbase[tid] = s[tid] - v;  // exclusive
}

__global__ __launch_bounds__(256) void kscan3(const int* __restrict__ deg,
                                              int* __restrict__ offs,  // in: incl, out: excl
                                              const int* __restrict__ bbase,
                                              int* __restrict__ cursor) {
  int i = blockIdx.x * 256 + threadIdx.x;
  if (i < N_NODES) {
    int v = offs[i] - deg[i] + bbase[i >> 8];
    offs[i] = v;
    cursor[i] = v;
  }
  if (i == 0) offs[N_NODES] = N_EDGES;
}

__global__ __launch_bounds__(256) void kscatter(const int* __restrict__ ei,
                                                const float* __restrict__ pseudo,
                                                int* __restrict__ cursor,
                                                uint2* __restrict__ epack) {
  int e = blockIdx.x * 256 + threadIdx.x;
  if (e >= N_EDGES) return;
  int r = ei[e];
  int c = ei[N_EDGES + e];
  int pos = atomicAdd(&cursor[r], 1);
  float p0 = pseudo[2 * e];
  float p1 = pseudo[2 * e + 1];
  uint32_t q0 = (uint32_t)__float2uint_rn(p0 * 65535.f);
  uint32_t q1 = (uint32_t)__float2uint_rn(p1 * 65535.f);
  uint2 pk;
  pk.x = (uint32_t)c;
  pk.y = q0 | (q1 << 16);
  epack[pos] = pk;
}

// ---------------------------------------------------------------------------
// K2: one 64-lane wave per target node; lanes 0-31 / 32-63 process alternate
// edges (lane=f_out within each half). Register accumulation, no atomics.
// out[node] += acc/(den+1e-16).
// ---------------------------------------------------------------------------
__global__ __launch_bounds__(256) void k2_csr(
    const int* __restrict__ offs, const uint2* __restrict__ epack,
    const unsigned short* __restrict__ xw, const float* __restrict__ r_dot,
    const float* __restrict__ att_w, float* __restrict__ out) {
  int tid = threadIdx.x;
  int wave = tid >> 6, lane = tid & 63;
  int node = blockIdx.x * 4 + wave;
  if (node >= N_NODES) return;
  int f = lane & 31, half = lane >> 5;
  float a2 = att_w[32 + f];
  float rd = r_dot[node];
  int s0 = offs[node], s1 = offs[node + 1];
  float acc = 0.f, den = 0.f;
  for (int i = s0 + half; i < s1; i += 2) {
    uint2 pk = epack[i];
    int col = (int)pk.x;
    float p0 = (float)(pk.y & 0xffffu) * (4.0f / 65535.0f);
    float p1 = (float)(pk.y >> 16) * (4.0f / 65535.0f);
    float fl0 = floorf(p0), fl1 = floorf(p1);
    float fr0 = p0 - fl0, fr1 = p1 - fl1;
    int i0 = (int)fl0, i1 = (int)fl1;
    const unsigned short* base = xw + (size_t)col * 800 + f;
    float msg = 0.f;
#pragma unroll
    for (int s = 0; s < 4; s++) {
      int o0 = s & 1, o1 = (s >> 1) & 1;
      int w = min(i0 + o0, 4) + 5 * min(i1 + o1, 4);
      float b = (o0 ? fr0 : 1.f - fr0) * (o1 ? fr1 : 1.f - fr1);
      msg += b * bf16_to_f32(base[w * 32]);
    }
    float v = msg * a2;
#pragma unroll
    for (int m = 16; m >= 1; m >>= 1) v += __shfl_xor(v, m);
    float alpha = rd + v;
    alpha = alpha > 0.f ? alpha : 0.2f * alpha;
    float ex = __expf(alpha);
    acc += msg * ex;
    den += ex;
  }
  acc += __shfl_xor(acc, 32);
  den += __shfl_xor(den, 32);
  if (half == 0) out[node * 32 + f] += acc / (den + 1e-16f);
}

extern "C" void kernel_launch(void* const* d_in, const int* in_sizes, int n_in,
                              void* d_out, int out_size, void* d_ws, size_t ws_size,
                              hipStream_t stream) {
  const float* x      = (const float*)d_in[0];
  const int*   ei     = (const int*)d_in[1];
  const float* pseudo = (const float*)d_in[2];
  const float* weight = (const float*)d_in[3];
  const float* root_w = (const float*)d_in[4];
  const float* att_w  = (const float*)d_in[5];
  const float* bias   = (const float*)d_in[6];
  float* out = (float*)d_out;

  char* ws = (char*)d_ws;
  unsigned short* xw  = (unsigned short*)ws;              // 160,000,000 B
  float* r_dot        = (float*)(ws + 160000000);         //    400,000 B
  unsigned short* wbf = (unsigned short*)(ws + 160400000);//     51,200 B
  int* deg            = (int*)(ws + 160451200);           //    400,000 B
  int* offs           = (int*)(ws + 160851200);           //    400,016 B (100001 ints)
  int* bsum           = (int*)(ws + 161251216);           //      1,600 B
  int* bbase          = (int*)(ws + 161252816);           //      1,600 B
  int* cursor         = (int*)(ws + 161254416);           //    400,000 B
  uint2* epack        = (uint2*)(ws + 161654416);         // 12,800,000 B -> end 174.5 MB

  hipLaunchKernelGGL(k0_node_pre, dim3(12500), dim3(256), 0, stream,
                     x, root_w, att_w, bias, out, r_dot, deg);
  hipLaunchKernelGGL(kw_swizzle, dim3(100), dim3(256), 0, stream, weight, wbf);
  hipLaunchKernelGGL(khist, dim3(6250), dim3(256), 0, stream, ei, deg);
  hipLaunchKernelGGL(kscan1, dim3(NBLK_SCAN), dim3(256), 0, stream, deg, offs, bsum);
  hipLaunchKernelGGL(kscan2, dim3(1), dim3(512), 0, stream, bsum, bbase);
  hipLaunchKernelGGL(kscan3, dim3(NBLK_SCAN), dim3(256), 0, stream, deg, offs, bbase, cursor);
  hipLaunchKernelGGL(kscatter, dim3(6250), dim3(256), 0, stream, ei, pseudo, cursor, epack);
  hipLaunchKernelGGL(k1_xw, dim3(6250), dim3(256), 0, stream, x, wbf, xw);
  hipLaunchKernelGGL(k2_csr, dim3(25000), dim3(256), 0, stream,
                     offs, epack, xw, r_dot, att_w, out);
}